// Round 1
// baseline (197.407 us; speedup 1.0000x reference)
//
#include <hip/hip_runtime.h>
#include <hip/hip_bf16.h>
#include <cmath>

// out[b] = X_b (Wq Wk^T) (X_b^T X_b) / 768^1.5   (47 GF factorized)
//   W16    = bf16(Wq), bf16(Wk)       (convert kernel)
//   P16    = Wq16 * Wk16^T            (glds staging; 64x64 tiles)
//   G16_b  = Xt_b * Xt_b^T            (96x96; SYMMETRIC: only y<=z tiles computed,
//                                      y<z mirrored via packed ushort4 stores)
//   Ht16_b = alpha * G16_b * P^T      (96x96, batch-pinned)
//   out_b  = Xbf_b * Ht16_b^T         (128x128, batch-pinned, fp32 out)
// MFMA bf16 16x16x32, BK=64, fp32 accumulate, glds width-16 staging,
// XOR chunk swizzle (bank-conflict-free, verified: SQ_LDS_BANK_CONFLICT=0).
// R1 change: 2-phase prefetch double-buffer (T3-minimum): STAGE(buf^1, t+1)
// issued BEFORE compute of tile t; ONE barrier per K-step. The old
// stage->sync->compute->sync structure drained vmcnt(0) with zero overlap,
// which at 1-2 blocks/CU (small grids) left every K-step staging-latency-bound.
// Batch in blockIdx.x => XCD = b%8 => per-XCD working set L2-resident.

typedef __attribute__((ext_vector_type(8))) short short8;
typedef __attribute__((ext_vector_type(4))) float f32x4;

__device__ __forceinline__ unsigned short f2bf(float f) {
    union { float f; unsigned int u; } v; v.f = f;
    unsigned int u = v.u;
    return (unsigned short)((u + 0x7FFFu + ((u >> 16) & 1u)) >> 16);  // RNE
}

// ---- Wq,Wk fp32 -> bf16 ----
__global__ __launch_bounds__(256)
void convert_w(const float* __restrict__ Wq, const float* __restrict__ Wk,
               unsigned short* __restrict__ Wq16, unsigned short* __restrict__ Wk16)
{
    int i = (blockIdx.x * 256 + threadIdx.x) * 8;   // 768*768 / 8 = 73728 threads
    float4 a = *reinterpret_cast<const float4*>(&Wq[i]);
    float4 b = *reinterpret_cast<const float4*>(&Wq[i + 4]);
    uint4 v;
    v.x = (unsigned)f2bf(a.x) | ((unsigned)f2bf(a.y) << 16);
    v.y = (unsigned)f2bf(a.z) | ((unsigned)f2bf(a.w) << 16);
    v.z = (unsigned)f2bf(b.x) | ((unsigned)f2bf(b.y) << 16);
    v.w = (unsigned)f2bf(b.z) | ((unsigned)f2bf(b.w) << 16);
    *reinterpret_cast<uint4*>(&Wq16[i]) = v;
    a = *reinterpret_cast<const float4*>(&Wk[i]);
    b = *reinterpret_cast<const float4*>(&Wk[i + 4]);
    v.x = (unsigned)f2bf(a.x) | ((unsigned)f2bf(a.y) << 16);
    v.y = (unsigned)f2bf(a.z) | ((unsigned)f2bf(a.w) << 16);
    v.z = (unsigned)f2bf(b.x) | ((unsigned)f2bf(b.y) << 16);
    v.w = (unsigned)f2bf(b.z) | ((unsigned)f2bf(b.w) << 16);
    *reinterpret_cast<uint4*>(&Wk16[i]) = v;
}

// ---- X[b][S][D] fp32 -> Xt[b][D][S] bf16 AND Xbf[b][S][D] bf16 ----
__global__ __launch_bounds__(256)
void transpose_bf16(const float* __restrict__ X, unsigned short* __restrict__ Xt,
                    unsigned short* __restrict__ Xbf, int S, int D)
{
    __shared__ unsigned short tile[32][36];
    const int b = blockIdx.z;
    const int s0 = blockIdx.x * 32;
    const int d0 = blockIdx.y * 32;
    const float* Xb = X + (size_t)b * S * D;
    unsigned short* Xtb = Xt + (size_t)b * S * D;
    unsigned short* Xbb = Xbf + (size_t)b * S * D;
    const int tx = threadIdx.x & 7;    // d-group (4 floats)
    const int ty = threadIdx.x >> 3;   // s 0..31

    float4 v = *reinterpret_cast<const float4*>(&Xb[(size_t)(s0 + ty) * D + d0 + tx * 4]);
    ushort4 pk;
    pk.x = f2bf(v.x); pk.y = f2bf(v.y); pk.z = f2bf(v.z); pk.w = f2bf(v.w);
    *reinterpret_cast<ushort4*>(&Xbb[(size_t)(s0 + ty) * D + d0 + tx * 4]) = pk;
    tile[tx * 4 + 0][ty] = pk.x;
    tile[tx * 4 + 1][ty] = pk.y;
    tile[tx * 4 + 2][ty] = pk.z;
    tile[tx * 4 + 3][ty] = pk.w;
    __syncthreads();
    ushort4 o;
    o.x = tile[ty][tx * 4 + 0];
    o.y = tile[ty][tx * 4 + 1];
    o.z = tile[ty][tx * 4 + 2];
    o.w = tile[ty][tx * 4 + 3];
    *reinterpret_cast<ushort4*>(&Xtb[(size_t)(d0 + ty) * S + s0 + tx * 4]) = o;
}

// ---- glds staging: ROWS x 64 bf16 tile -> LDS, 16B chunks, XOR swizzle ----
template <int ROWS>
__device__ __forceinline__ void stage_glds(const unsigned short* src, unsigned short* lds,
                                           int ld, int tid)
{
    #pragma unroll
    for (int it = 0; it < ROWS / 32; ++it) {
        int slot = it * 256 + tid;
        int r = slot >> 3, c = slot & 7;
        const unsigned short* gp = src + (size_t)r * ld + ((c ^ (r & 7)) << 3);
        unsigned short* lp = lds + (size_t)(it * 256 + (tid & 192)) * 8;  // wave-uniform base
        __builtin_amdgcn_global_load_lds(
            (__attribute__((address_space(1))) void*)(void*)gp,
            (__attribute__((address_space(3))) void*)lp, 16, 0, 0);
    }
}

__device__ __forceinline__ void store_c(float* C, size_t i, float v) { C[i] = v; }
__device__ __forceinline__ void store_c(unsigned short* C, size_t i, float v) { C[i] = f2bf(v); }

// C = alpha * A[M,K] * Bt[N,K]^T ; row-major.
// Grid = (batch, rowTiles, colTiles): batch in blockIdx.x pins batch->XCD (b%8).
// SYMM: A==B and C symmetric -> compute only y<=z tiles, mirror y<z tiles.
// 2-phase prefetch: stage K-tile t+1 into buf^1 while computing tile t from buf.
template <int TM, int TN, bool SYMM, typename CT>
__global__ __launch_bounds__(256)
void gemm(const unsigned short* __restrict__ Ap, const unsigned short* __restrict__ Bp,
          CT* __restrict__ Cb,
          int Kloop, int lda, int ldb, int ldc, long sA, long sB, long sC, float alpha)
{
    constexpr int FM = TM / 32;
    constexpr int FN = TN / 32;
    if (SYMM && blockIdx.y > blockIdx.z) return;   // upper triangle only
    const int b = blockIdx.x;
    CT* C = Cb + (long)b * sC;

    __shared__ unsigned short Alds[2][TM * 64];
    __shared__ unsigned short Blds[2][TN * 64];

    const int tid  = threadIdx.x;
    const int lane = tid & 63;
    const int wave = tid >> 6;
    const int wr   = (wave >> 1) * (TM / 2);
    const int wc   = (wave & 1) * (TN / 2);
    const int rowBase = blockIdx.y * TM;
    const int colBase = blockIdx.z * TN;
    const int l15  = lane & 15;
    const int quad = lane >> 4;

    const unsigned short* Abase = Ap + (long)b * sA + (size_t)rowBase * lda;
    const unsigned short* Bbase = Bp + (long)b * sB + (size_t)colBase * ldb;

    f32x4 acc[FM][FN] = {};

    // prologue: stage K-tile 0 into buffer 0
    stage_glds<TM>(Abase, &Alds[0][0], lda, tid);
    stage_glds<TN>(Bbase, &Blds[0][0], ldb, tid);
    __syncthreads();

    const int nt = Kloop >> 6;
    for (int t = 0; t < nt; ++t) {
        const int cur = t & 1;
        // issue next-tile staging FIRST; it drains at the barrier below,
        // after the whole compute phase has run on top of it.
        if (t + 1 < nt) {
            stage_glds<TM>(Abase + (t + 1) * 64, &Alds[cur ^ 1][0], lda, tid);
            stage_glds<TN>(Bbase + (t + 1) * 64, &Blds[cur ^ 1][0], ldb, tid);
        }

        short8 af[FM][2], bfr[FN][2];
        #pragma unroll
        for (int i = 0; i < FM; ++i) {
            int ra = wr + i * 16 + l15;
            af[i][0] = *reinterpret_cast<const short8*>(&Alds[cur][ra * 64 + ((quad ^ (ra & 7)) << 3)]);
            af[i][1] = *reinterpret_cast<const short8*>(&Alds[cur][ra * 64 + (((quad + 4) ^ (ra & 7)) << 3)]);
        }
        #pragma unroll
        for (int i = 0; i < FN; ++i) {
            int rb = wc + i * 16 + l15;
            bfr[i][0] = *reinterpret_cast<const short8*>(&Blds[cur][rb * 64 + ((quad ^ (rb & 7)) << 3)]);
            bfr[i][1] = *reinterpret_cast<const short8*>(&Blds[cur][rb * 64 + (((quad + 4) ^ (rb & 7)) << 3)]);
        }
        #pragma unroll
        for (int ks = 0; ks < 2; ++ks)
            #pragma unroll
            for (int mi = 0; mi < FM; ++mi)
                #pragma unroll
                for (int ni = 0; ni < FN; ++ni)
                    acc[mi][ni] = __builtin_amdgcn_mfma_f32_16x16x32_bf16(
                        af[mi][ks], bfr[ni][ks], acc[mi][ni], 0, 0, 0);

        // one barrier per K-step: drains vmcnt(0) (next tile landed) and
        // guarantees all waves finished reading buf[cur] before t+1 overwrites it.
        __syncthreads();
    }

    // C/D layout (m89-verified): col = lane&15, row = quad*4 + reg
    #pragma unroll
    for (int mi = 0; mi < FM; ++mi) {
        #pragma unroll
        for (int ni = 0; ni < FN; ++ni) {
            int col = colBase + wc + ni * 16 + l15;
            #pragma unroll
            for (int r = 0; r < 4; ++r) {
                int row = rowBase + wr + mi * 16 + quad * 4 + r;
                store_c(C, (size_t)row * ldc + col, alpha * acc[mi][ni][r]);
            }
            if constexpr (SYMM) {
                // mirror tile (z,y) <- transpose: 4 consecutive rows of this lane
                // become 4 consecutive cols at row `col` -> packed 8B store, 4-aligned.
                if (blockIdx.y < blockIdx.z) {
                    ushort4 m;
                    m.x = f2bf(alpha * acc[mi][ni][0]);
                    m.y = f2bf(alpha * acc[mi][ni][1]);
                    m.z = f2bf(alpha * acc[mi][ni][2]);
                    m.w = f2bf(alpha * acc[mi][ni][3]);
                    size_t mbase = (size_t)col * ldc + rowBase + wr + mi * 16 + quad * 4;
                    *reinterpret_cast<ushort4*>(&((unsigned short*)C)[mbase]) = m;
                }
            }
        }
    }
}

extern "C" void kernel_launch(void* const* d_in, const int* in_sizes, int n_in,
                              void* d_out, int out_size, void* d_ws, size_t ws_size,
                              hipStream_t stream)
{
    const float* X  = (const float*)d_in[0];  // [8,2048,768] fp32
    const float* Wq = (const float*)d_in[2];  // [768,768]
    const float* Wk = (const float*)d_in[3];  // [768,768]
    float* out = (float*)d_out;               // [8,2048,768] fp32

    const int Bn = 8, S = 2048, D = 768;
    const float alpha = 1.0f / (768.0f * sqrtf(768.0f));  // 1/768^1.5
    const size_t szX  = (size_t)Bn * S * D;   // ushort elements
    const size_t szDD = (size_t)Bn * D * D;

    // ws: Xt16 | Xbf | P16 | G16 | Ht16 | Wq16 | Wk16  (~72.9 MB)
    unsigned short* Xt16 = (unsigned short*)d_ws;
    unsigned short* Xbf  = Xt16 + szX;
    unsigned short* P16  = Xbf + szX;
    unsigned short* G16  = P16 + (size_t)D * D;
    unsigned short* Ht16 = G16 + szDD;
    unsigned short* Wq16 = Ht16 + szDD;
    unsigned short* Wk16 = Wq16 + (size_t)D * D;

    convert_w<<<dim3(D * D / 2048, 1, 1), 256, 0, stream>>>(Wq, Wk, Wq16, Wk16);

    transpose_bf16<<<dim3(S / 32, D / 32, Bn), 256, 0, stream>>>(X, Xt16, Xbf, S, D);

    // P = Wq16 * Wk16^T   (grid (1,12,12))
    gemm<64, 64, false, unsigned short><<<dim3(1, 12, 12), 256, 0, stream>>>(
        Wq16, Wk16, P16, D, D, D, D, 0L, 0L, 0L, 1.0f);

    // G_b = Xt_b * Xt_b^T   (K = 2048; symmetric: y<=z computed, y<z mirrored)
    gemm<96, 96, true, unsigned short><<<dim3(Bn, 8, 8), 256, 0, stream>>>(
        Xt16, Xt16, G16, S, S, S, D, (long)D * S, (long)D * S, (long)D * D, 1.0f);

    // Ht_b = alpha * G_b * P^T  (== H^T since G symmetric; batch-pinned)
    gemm<96, 96, false, unsigned short><<<dim3(Bn, 8, 8), 256, 0, stream>>>(
        G16, P16, Ht16, D, D, D, D, (long)D * D, 0L, (long)D * D, alpha);

    // out_b = Xbf_b * Ht_b^T   (batch-pinned grid (8,16,6))
    gemm<128, 128, false, float><<<dim3(Bn, S / 128, 6), 256, 0, stream>>>(
        Xbf, Ht16, out, D, D, D, D, (long)S * D, (long)D * D, (long)S * D, 1.0f);
}